// Round 4
// baseline (297.975 us; speedup 1.0000x reference)
//
#include <hip/hip_runtime.h>
#include <hip/hip_bf16.h>
#include <stdint.h>

// Problem constants
#define BATCH 64
#define IN_CAPS 512          // In (input capsules)
#define NCAP 16              // num_capsule
#define DCAP 64              // dim_capsule
#define GN (NCAP * DCAP)     // 1024
#define GM (BATCH * IN_CAPS) // 32768
#define GK 768               // input feature dim (K)

typedef __bf16 bf16;
typedef __attribute__((ext_vector_type(8))) __bf16 bf16x8;
typedef __attribute__((ext_vector_type(4))) __bf16 bf16x4;
typedef __attribute__((ext_vector_type(4))) float f32x4;

// ---------------------------------------------------------------------------
// Kernel 0: input dtype detection. flag=1 => inputs are bf16, 0 => fp32.
// (Round-1 NaN already proved fp32; this is cheap insurance.)
// ---------------------------------------------------------------------------
__global__ void k_detect(const uint32_t* __restrict__ X32, int* __restrict__ flag) {
    const int lane = threadIdx.x; // 64 threads, 1 block
    int cnt = 0;
#pragma unroll
    for (int i = 0; i < 4; ++i) {
        const uint32_t w = X32[lane * 4 + i];
        const uint32_t e = (w >> 7) & 0xFF; // exponent of low halfword as bf16
        cnt += (e >= 119 && e <= 130) ? 1 : 0;
    }
#pragma unroll
    for (int off = 32; off >= 1; off >>= 1) cnt += __shfl_xor(cnt, off);
    if (lane == 0) *flag = (cnt > 128) ? 1 : 0;
}

// ---------------------------------------------------------------------------
// Kernel 1: transpose W [768][1024](T) -> Wt [1024][768] bf16 (K-contiguous).
// ---------------------------------------------------------------------------
template <typename T>
__global__ void k_transW(const T* __restrict__ W, bf16* __restrict__ Wt,
                         const int* __restrict__ flag, int want) {
    if (*flag != want) return; // wave-uniform
    __shared__ bf16 t[32][33];
    const int k0 = blockIdx.x * 32;
    const int n0 = blockIdx.y * 32;
    const int tx = threadIdx.x, ty = threadIdx.y;
#pragma unroll
    for (int r = 0; r < 4; ++r)
        t[ty + r * 8][tx] = (bf16)(float)W[(size_t)(k0 + ty + r * 8) * GN + n0 + tx];
    __syncthreads();
#pragma unroll
    for (int r = 0; r < 4; ++r)
        Wt[(size_t)(n0 + ty + r * 8) * GK + k0 + tx] = t[tx][ty + r * 8];
}

// 8-element loaders producing bf16x8 regardless of source dtype
__device__ inline bf16x8 load8(const bf16* p) { return *(const bf16x8*)p; }
__device__ inline bf16x8 load8(const float* p) {
    const f32x4 a = *(const f32x4*)p;
    const f32x4 b = *(const f32x4*)(p + 4);
    bf16x8 r;
    r[0] = (bf16)a[0]; r[1] = (bf16)a[1]; r[2] = (bf16)a[2]; r[3] = (bf16)a[3];
    r[4] = (bf16)b[0]; r[5] = (bf16)b[1]; r[6] = (bf16)b[2]; r[7] = (bf16)b[3];
    return r;
}

// ---------------------------------------------------------------------------
// Kernel 2: MFMA bf16 GEMM  U = X @ W  (empirically validated: round2==round3)
//   U: [b][cap][j][k] bf16   (b = m>>9, j = m&511, cap = n>>6, k = n&63)
// 128x128 tile, BK=32, 256 threads (4 waves 2x2), 4x4 frags of 16x16x32.
// ---------------------------------------------------------------------------
template <typename T>
__global__ __launch_bounds__(256) void k_gemm(const T* __restrict__ X,
                                              const bf16* __restrict__ Wt,
                                              bf16* __restrict__ U,
                                              const int* __restrict__ flag, int want) {
    if (*flag != want) return; // wave-uniform
    __shared__ bf16 sA[128 * 32];
    __shared__ bf16 sB[128 * 32];

    const int tid = threadIdx.x;
    const int lane = tid & 63;
    const int wave = tid >> 6;
    const int wm = wave >> 1, wn = wave & 1;
    const int m0 = blockIdx.x * 128;
    const int n0 = blockIdx.y * 128;

    const int srow = tid >> 2;      // 0..63
    const int scol = (tid & 3) * 8; // 0,8,16,24 (elements)

    f32x4 acc[4][4] = {};

    const int fr = lane & 15; // m (A) / n (B,D) within 16-tile
    const int fq = lane >> 4; // quad: k offset fq*8 (A/B), D row base fq*4

    for (int kt = 0; kt < GK / 32; ++kt) {
        const int kb = kt * 32;
        const bf16x8 a0 = load8(X + (size_t)(m0 + srow) * GK + kb + scol);
        const bf16x8 a1 = load8(X + (size_t)(m0 + srow + 64) * GK + kb + scol);
        const bf16x8 b0 = load8(Wt + (size_t)(n0 + srow) * GK + kb + scol);
        const bf16x8 b1 = load8(Wt + (size_t)(n0 + srow + 64) * GK + kb + scol);

        __syncthreads();
        *(bf16x8*)(sA + srow * 32 + scol) = a0;
        *(bf16x8*)(sA + (srow + 64) * 32 + scol) = a1;
        *(bf16x8*)(sB + srow * 32 + scol) = b0;
        *(bf16x8*)(sB + (srow + 64) * 32 + scol) = b1;
        __syncthreads();

        bf16x8 af[4], bfr[4];
#pragma unroll
        for (int mi = 0; mi < 4; ++mi)
            af[mi] = *(const bf16x8*)(sA + (wm * 64 + mi * 16 + fr) * 32 + fq * 8);
#pragma unroll
        for (int ni = 0; ni < 4; ++ni)
            bfr[ni] = *(const bf16x8*)(sB + (wn * 64 + ni * 16 + fr) * 32 + fq * 8);
#pragma unroll
        for (int mi = 0; mi < 4; ++mi)
#pragma unroll
            for (int ni = 0; ni < 4; ++ni)
                acc[mi][ni] = __builtin_amdgcn_mfma_f32_16x16x32_bf16(
                    af[mi], bfr[ni], acc[mi][ni], 0, 0, 0);
    }

    // epilogue: D layout col(n)=lane&15, row(m)=(lane>>4)*4+r -> scatter to U
#pragma unroll
    for (int mi = 0; mi < 4; ++mi) {
#pragma unroll
        for (int ni = 0; ni < 4; ++ni) {
#pragma unroll
            for (int r = 0; r < 4; ++r) {
                const int m = m0 + wm * 64 + mi * 16 + fq * 4 + r;
                const int n = n0 + wn * 64 + ni * 16 + fr;
                const int bb = m >> 9, j = m & 511;
                const int ci = n >> 6, k = n & 63;
                U[(((size_t)(bb * NCAP + ci)) * IN_CAPS + j) * DCAP + k] =
                    (bf16)acc[mi][ni][r];
            }
        }
    }
}

// ---------------------------------------------------------------------------
// Kernel 3: out-pass. Block per (b,cap). outputs[k] = squash(sum_j c[j]*u[j][k])
// Writes OutF (fp32 scratch, read by logits) and OutC (fp32 d_out).
// ---------------------------------------------------------------------------
__global__ __launch_bounds__(256) void k_caps_out(const bf16* __restrict__ U,
                                                  const float* __restrict__ C,
                                                  float* __restrict__ OutF,
                                                  float* __restrict__ OutC,
                                                  int useC) {
    const int bi = blockIdx.x; // b*16 + cap
    const int tid = threadIdx.x;
    const int lane = tid & 63, wave = tid >> 6;
    const int kq = lane & 15, jj = lane >> 4;
    const size_t ubase = (size_t)bi * IN_CAPS * DCAP;

    float a0 = 0.f, a1 = 0.f, a2 = 0.f, a3 = 0.f;
#pragma unroll 4
    for (int it = 0; it < 32; ++it) {
        const int j = it * 16 + wave * 4 + jj;
        const bf16x4 v = *(const bf16x4*)(U + ubase + (size_t)j * DCAP + kq * 4);
        const float cv = useC ? C[(size_t)bi * IN_CAPS + j] : 0.0625f;
        a0 += cv * (float)v[0];
        a1 += cv * (float)v[1];
        a2 += cv * (float)v[2];
        a3 += cv * (float)v[3];
    }

    __shared__ float red[16][64];
    const int p = wave * 4 + jj;
    red[p][kq * 4 + 0] = a0;
    red[p][kq * 4 + 1] = a1;
    red[p][kq * 4 + 2] = a2;
    red[p][kq * 4 + 3] = a3;
    __syncthreads();

    if (wave == 0) {
        float s = 0.f;
#pragma unroll
        for (int q = 0; q < 16; ++q) s += red[q][lane];
        float ss = s * s;
#pragma unroll
        for (int off = 32; off >= 1; off >>= 1) ss += __shfl_xor(ss, off);
        const float val = s * rsqrtf(ss + 1e-7f);
        OutF[(size_t)bi * DCAP + lane] = val;
        OutC[(size_t)bi * DCAP + lane] = val; // fp32 output
    }
}

// ---------------------------------------------------------------------------
// Kernel 4: logits. Block per (b,cap). bl[j] = sum_k outputs[k]*u[j][k]
// ---------------------------------------------------------------------------
__global__ __launch_bounds__(256) void k_caps_logits(const bf16* __restrict__ U,
                                                     const float* __restrict__ OutF,
                                                     float* __restrict__ BL) {
    const int bi = blockIdx.x;
    const int tid = threadIdx.x;
    const int lane = tid & 63, wave = tid >> 6;
    const int kq = lane & 15, jj = lane >> 4;
    const size_t ubase = (size_t)bi * IN_CAPS * DCAP;

    const float4 ov = *(const float4*)(OutF + (size_t)bi * DCAP + kq * 4);
#pragma unroll 4
    for (int it = 0; it < 32; ++it) {
        const int j = it * 16 + wave * 4 + jj;
        const bf16x4 v = *(const bf16x4*)(U + ubase + (size_t)j * DCAP + kq * 4);
        float p = ov.x * (float)v[0] + ov.y * (float)v[1] +
                  ov.z * (float)v[2] + ov.w * (float)v[3];
        p += __shfl_xor(p, 1);
        p += __shfl_xor(p, 2);
        p += __shfl_xor(p, 4);
        p += __shfl_xor(p, 8);
        if (kq == 0) BL[(size_t)bi * IN_CAPS + j] = p;
    }
}

// ---------------------------------------------------------------------------
// Kernel 5: softmax over the 16-capsule axis, in place on BL.
// ---------------------------------------------------------------------------
__global__ __launch_bounds__(256) void k_softmax(float* __restrict__ BL) {
    const int t = blockIdx.x * 256 + threadIdx.x;
    const int b = t >> 9, j = t & 511;
    float* p = BL + (size_t)b * NCAP * IN_CAPS + j;
    float v[16];
    float m = -1e30f;
#pragma unroll
    for (int i = 0; i < 16; ++i) {
        v[i] = p[(size_t)i * IN_CAPS];
        m = fmaxf(m, v[i]);
    }
    float s = 0.f;
#pragma unroll
    for (int i = 0; i < 16; ++i) {
        v[i] = __expf(v[i] - m);
        s += v[i];
    }
    const float inv = 1.0f / s;
#pragma unroll
    for (int i = 0; i < 16; ++i) p[(size_t)i * IN_CAPS] = v[i] * inv;
}

// ---------------------------------------------------------------------------
extern "C" void kernel_launch(void* const* d_in, const int* in_sizes, int n_in,
                              void* d_out, int out_size, void* d_ws, size_t ws_size,
                              hipStream_t stream) {
    float* OutC = (float*)d_out; // [64][16][64] fp32 (reference output dtype)

    // workspace layout
    const size_t u_bytes = (size_t)BATCH * NCAP * IN_CAPS * DCAP * sizeof(bf16); // 64 MiB
    const size_t wt_bytes = (size_t)GN * GK * sizeof(bf16);                      // 1.5 MiB
    const size_t outf_bytes = (size_t)BATCH * NCAP * DCAP * sizeof(float);       // 256 KiB
    const size_t bl_bytes = (size_t)BATCH * NCAP * IN_CAPS * sizeof(float);      // 2 MiB
    char* ws = (char*)d_ws;
    bf16* U = (bf16*)ws;
    bf16* Wt = (bf16*)(ws + u_bytes);
    float* OutF = (float*)(ws + u_bytes + wt_bytes);
    float* BL = (float*)(ws + u_bytes + wt_bytes + outf_bytes);
    int* flag = (int*)(ws + u_bytes + wt_bytes + outf_bytes + bl_bytes);
    if (ws_size < u_bytes + wt_bytes + outf_bytes + bl_bytes + 256) return;

    // 0) dtype detect
    k_detect<<<1, 64, 0, stream>>>((const uint32_t*)d_in[0], flag);

    // 1) W transpose (both dtype variants; wrong one exits on flag)
    k_transW<bf16><<<dim3(GK / 32, GN / 32), dim3(32, 8), 0, stream>>>(
        (const bf16*)d_in[1], Wt, flag, 1);
    k_transW<float><<<dim3(GK / 32, GN / 32), dim3(32, 8), 0, stream>>>(
        (const float*)d_in[1], Wt, flag, 0);

    // 2) GEMM (both dtype variants)
    k_gemm<bf16><<<dim3(GM / 128, GN / 128), 256, 0, stream>>>(
        (const bf16*)d_in[0], Wt, U, flag, 1);
    k_gemm<float><<<dim3(GM / 128, GN / 128), 256, 0, stream>>>(
        (const float*)d_in[0], Wt, U, flag, 0);

    // 3) routing iter 0 (uniform c = 1/16)
    k_caps_out<<<BATCH * NCAP, 256, 0, stream>>>(U, BL, OutF, OutC, 0);
    k_caps_logits<<<BATCH * NCAP, 256, 0, stream>>>(U, OutF, BL);
    k_softmax<<<BATCH * IN_CAPS / 256, 256, 0, stream>>>(BL);
    // iter 1
    k_caps_out<<<BATCH * NCAP, 256, 0, stream>>>(U, BL, OutF, OutC, 1);
    k_caps_logits<<<BATCH * NCAP, 256, 0, stream>>>(U, OutF, BL);
    k_softmax<<<BATCH * IN_CAPS / 256, 256, 0, stream>>>(BL);
    // iter 2 (final)
    k_caps_out<<<BATCH * NCAP, 256, 0, stream>>>(U, BL, OutF, OutC, 1);
}